// Round 6
// baseline (463.052 us; speedup 1.0000x reference)
//
#include <hip/hip_runtime.h>

#define DIN 256
#define H   128
#define DOUT 64

#define EPI_RELU 0
#define EPI_BN   1
#define EPI_NONE 2

#define BKT_SHIFT 7                 // 128 nodes per bucket
#define BKT_NODES 128
#define BKT_CAP   4096              // slots per bucket (mean 2048, sigma ~45)
#define CSR_CAP   4608              // BKT_CAP + 128*3 align slack + 16 tail pad

typedef __attribute__((ext_vector_type(8))) short bf16x8;
typedef __attribute__((ext_vector_type(4))) float f32x4;

__device__ inline unsigned short f2bf(float f) {
  union { float f; unsigned u; } v; v.f = f;
  unsigned u = v.u;
  u += 0x7FFFu + ((u >> 16) & 1u);   // round-to-nearest-even
  return (unsigned short)(u >> 16);
}
__device__ inline float bf2f(unsigned u16) {
  union { unsigned u; float f; } v; v.u = u16 << 16;
  return v.f;
}
// pack two fp32 -> one u32 of 2x bf16, RNE via verified bit-twiddle
__device__ inline unsigned pk_bf16(float lo, float hi) {
  return (unsigned)f2bf(lo) | ((unsigned)f2bf(hi) << 16);
}

// async global->LDS DMA, 16B per lane; LDS dest = wave-uniform base + lane*16
__device__ inline void gload_lds16(const void* g, void* l) {
  __builtin_amdgcn_global_load_lds(
      (const __attribute__((address_space(1))) void*)g,
      (__attribute__((address_space(3))) void*)l, 16, 0, 0);
}

// ---------------- stage 1: bucket edges by dst>>7 ----------------
#define FILL_TPB 1024
#define FILL_EPT 16
#define FILL_EPB (FILL_TPB * FILL_EPT)

__global__ __launch_bounds__(FILL_TPB) void bucket_fill(
    const int* __restrict__ src, const int* __restrict__ dst,
    int* __restrict__ bcur, unsigned* __restrict__ bedges,
    int nbkt, int e) {
  __shared__ int hist[1024];        // >= nbkt (782)
  int tid = threadIdx.x;
  int base = blockIdx.x * FILL_EPB;
  for (int i = tid; i < nbkt; i += FILL_TPB) hist[i] = 0;
  __syncthreads();

  int es[FILL_EPT], ed[FILL_EPT];
#pragma unroll
  for (int j = 0; j < FILL_EPT; ++j) {
    int i = base + j * FILL_TPB + tid;
    if (i < e) {
      es[j] = src[i];
      ed[j] = dst[i];
      atomicAdd(&hist[ed[j] >> BKT_SHIFT], 1);
    } else {
      es[j] = -1; ed[j] = 0;
    }
  }
  __syncthreads();
  for (int b = tid; b < nbkt; b += FILL_TPB) {
    int cnt = hist[b];
    hist[b] = cnt ? atomicAdd(&bcur[b], cnt) : 0;
  }
  __syncthreads();
#pragma unroll
  for (int j = 0; j < FILL_EPT; ++j) {
    if (es[j] >= 0) {
      int b = ed[j] >> BKT_SHIFT;
      int p = atomicAdd(&hist[b], 1);
      if (p < BKT_CAP)
        bedges[(size_t)b * BKT_CAP + p] =
            (unsigned)es[j] | ((unsigned)(ed[j] & (BKT_NODES - 1)) << 17);
    }
  }
}

// ---------------- stage 2: in-LDS counting sort per bucket -> aligned CSR ----
__global__ __launch_bounds__(256) void bucket_sort(
    const int* __restrict__ bcur, const unsigned* __restrict__ bedges,
    int* __restrict__ csr, int2* __restrict__ rowdeg, int n) {
  __shared__ unsigned rec[BKT_CAP];
  __shared__ int srcs[CSR_CAP];
  __shared__ int hist[BKT_NODES];
  __shared__ int cursor[BKT_NODES];
  __shared__ int s_total;
  int tid = threadIdx.x;
  int b = blockIdx.x;
  int cnt = bcur[b];
  if (cnt > BKT_CAP) cnt = BKT_CAP;
  const unsigned* eb = bedges + (size_t)b * BKT_CAP;

  if (tid < BKT_NODES) hist[tid] = 0;
  __syncthreads();
  for (int i = tid; i < cnt; i += 256) {
    unsigned r = eb[i];
    rec[i] = r;
    atomicAdd(&hist[(r >> 17) & 127], 1);
  }
  __syncthreads();
  int myc = (tid < BKT_NODES) ? hist[tid] : 0;
  int myc4 = (myc + 3) & ~3;        // 16B-aligned row length
  if (tid < BKT_NODES) hist[tid] = myc4;
  __syncthreads();
#pragma unroll
  for (int off = 1; off < BKT_NODES; off <<= 1) {
    int v = 0;
    if (tid < BKT_NODES && tid >= off) v = hist[tid - off];
    __syncthreads();
    if (tid < BKT_NODES) hist[tid] += v;
    __syncthreads();
  }
  int start = 0;
  if (tid < BKT_NODES) {
    start = hist[tid] - myc4;
    cursor[tid] = start;
    int node = b * BKT_NODES + tid;
    if (node < n) rowdeg[node] = make_int2(b * CSR_CAP + start, myc);
    if (tid == BKT_NODES - 1) s_total = hist[tid];
  }
  __syncthreads();
  for (int i = tid; i < cnt; i += 256) {
    unsigned r = rec[i];
    int p = atomicAdd(&cursor[(r >> 17) & 127], 1);
    srcs[p] = (int)(r & 0x1FFFFu);
  }
  // zero alignment gaps (disjoint from scatter targets, no sync needed)
  if (tid < BKT_NODES) {
    for (int g = start + myc; g < start + myc4; ++g) srcs[g] = 0;
  }
  __syncthreads();
  int total = s_total;
  if (tid < 16 && total + tid < CSR_CAP) srcs[total + tid] = 0;  // tail pad
  __syncthreads();
  int tot16 = total + 16;
  if (tot16 > CSR_CAP) tot16 = CSR_CAP;
  for (int i = tid; i < tot16; i += 256)
    csr[(size_t)b * CSR_CAP + i] = srcs[i];
}

// ---------------- mean aggregation: 4 nodes/wave, uint4 gather --------------
__global__ __launch_bounds__(256) void agg_kernel(
    const unsigned* __restrict__ h, const int2* __restrict__ rowdeg,
    const int* __restrict__ csr, unsigned* __restrict__ mean, int n) {
  int wid = (blockIdx.x * 256 + threadIdx.x) >> 6;
  int lane = threadIdx.x & 63;
  int grp = lane >> 4;
  int c = lane & 15;
  int node = wid * 4 + grp;
  bool valid = node < n;
  if (!valid) node = 0;
  int2 rd = rowdeg[node];
  int beg = rd.x, d = rd.y;

  const uint4* hv = (const uint4*)h;
  float a[8];
#pragma unroll
  for (int k = 0; k < 8; ++k) a[k] = 0.f;

  for (int j0 = 0; j0 < d; j0 += 16) {
    int rem = d - j0;
    const int4* sp = (const int4*)(csr + beg + j0);   // 16B aligned
    int sv[16];
    *(int4*)&sv[0]  = sp[0];
    *(int4*)&sv[4]  = sp[1];
    *(int4*)&sv[8]  = sp[2];
    *(int4*)&sv[12] = sp[3];
#pragma unroll
    for (int jj = 0; jj < 16; ++jj) {
      float w = (jj < rem) ? 1.f : 0.f;
      uint4 v = hv[(unsigned)(sv[jj] * 16 + c)];
#pragma unroll
      for (int k = 0; k < 4; ++k) {
        unsigned u = ((const unsigned*)&v)[k];
        union { unsigned u; float f; } lo, hi;
        lo.u = u << 16;
        hi.u = u & 0xffff0000u;
        a[2 * k]     = fmaf(w, lo.f, a[2 * k]);
        a[2 * k + 1] = fmaf(w, hi.f, a[2 * k + 1]);
      }
    }
  }

  if (valid) {
    float invd = 1.f / (float)(d > 0 ? d : 1);
    uint4 o;
    o.x = pk_bf16(a[0] * invd, a[1] * invd);
    o.y = pk_bf16(a[2] * invd, a[3] * invd);
    o.z = pk_bf16(a[4] * invd, a[5] * invd);
    o.w = pk_bf16(a[6] * invd, a[7] * invd);
    ((uint4*)mean)[(unsigned)(node * 16 + c)] = o;
  }
}

// ---------------- weight preconvert: Wt[m][k] = bf16(W[k][m]) ----------------
__global__ __launch_bounds__(256) void prep_w(
    const float* __restrict__ w_in, const float* __restrict__ w_l1,
    const float* __restrict__ w_r1, const float* __restrict__ w_l2,
    const float* __restrict__ w_r2, const float* __restrict__ w_out,
    unsigned short* __restrict__ t_in, unsigned short* __restrict__ t_l1,
    unsigned short* __restrict__ t_r1, unsigned short* __restrict__ t_l2,
    unsigned short* __restrict__ t_r2, unsigned short* __restrict__ t_out) {
  int i = blockIdx.x * 256 + threadIdx.x;
  const float* s; unsigned short* d; int K, M, off;
  if (i < 32768)       { s = w_in;  d = t_in;  K = 256; M = 128; off = i; }
  else if (i < 49152)  { s = w_l1;  d = t_l1;  K = 128; M = 128; off = i - 32768; }
  else if (i < 65536)  { s = w_r1;  d = t_r1;  K = 128; M = 128; off = i - 49152; }
  else if (i < 81920)  { s = w_l2;  d = t_l2;  K = 128; M = 128; off = i - 65536; }
  else if (i < 98304)  { s = w_r2;  d = t_r2;  K = 128; M = 128; off = i - 81920; }
  else if (i < 106496) { s = w_out; d = t_out; K = 128; M = 64;  off = i - 98304; }
  else return;
  int m = off / K, k = off % K;
  d[off] = f2bf(s[(size_t)k * M + m]);
}

// ------------- bf16 MFMA GEMM v5: persistent weights, barrier-free ----------
// All weights (NS streams, M x K each) staged to LDS ONCE per block via the
// verified DMA + pre-swizzled-source mechanism, then ONE barrier, then each
// wave grid-strides over 16-row tiles with a 2-stage ping-pong pipeline:
// A-frags for tile t+1 are issued while tile t computes. No barriers in the
// loop -> A-stream loads stay continuously in flight (8-16KB per wave),
// unlike v4's per-phase vmcnt(0)+barrier convoy (MfmaUtil 3.7%, HBM 15%).
// Frag layout, LDS swizzle chunk'=(ch+row)&(CH-1), and epilogue are
// bit-identical to the passing v4b.
template <int K, int M, int NS, int EPI, bool AFP32, bool OUTF32>
__global__ __launch_bounds__(256) void gemm_persist(
    const void* __restrict__ A1, const void* __restrict__ A2,
    const unsigned short* __restrict__ W1, const unsigned short* __restrict__ W2,
    const float* __restrict__ bias, const float* __restrict__ gamma,
    const float* __restrict__ beta, void* __restrict__ Cv,
    int n, int ntiles) {
  constexpr int NT = M / 16;        // output col tiles
  constexpr int KT = K / 32;        // k-steps
  constexpr int CH = K / 8;         // 16B chunks per weight row
  constexpr int RPI = 64 / CH;      // weight rows per DMA instruction
  constexpr int NI = (NS * M) / RPI;
  __shared__ __align__(16) unsigned short Bs[NS * M * K];

  int tid = threadIdx.x, lane = tid & 63, wave = tid >> 6;
  int m16 = lane & 15, quad = lane >> 4;

  // ---- one-time weight stage (DMA, pre-swizzled source; v4b-verified) ----
#pragma unroll
  for (int g = 0; g < NI / 4; ++g) {
    int i = g * 4 + wave;
    int r0 = i * RPI;                       // wave-uniform dest row
    int lr = r0 + lane / CH;                // per-lane weight row
    int sc = lane & (CH - 1);               // dest chunk
    int cs = (sc - lr) & (CH - 1);          // pre-swizzled source chunk
    const unsigned short* Ws = (NS == 2 && lr >= M) ? W2 : W1;
    int lrs = lr & (M - 1);
    gload_lds16(Ws + (size_t)lrs * K + cs * 8, &Bs[r0 * K]);
  }

  // ---- hoist epilogue constants (overlaps DMA) ----
  const float inv_std = rsqrtf(1.f + 1e-5f);
  float bv[NT], s2[NT], b2[NT];
#pragma unroll
  for (int t = 0; t < NT; ++t) {
    int col = t * 16 + m16;
    bv[t] = bias[col];
    if constexpr (EPI == EPI_BN) {
      s2[t] = gamma[col] * inv_std;
      b2[t] = beta[col];
    } else {
      s2[t] = 1.f; b2[t] = 0.f;
    }
  }
  __syncthreads();                          // weights resident; last barrier

  // ---- helpers (all array indices compile-time via full unroll) ----
  auto STORE = [&](f32x4 (&acc)[NT], int t) {
#pragma unroll
    for (int tt = 0; tt < NT; ++tt) {
      int col = tt * 16 + m16;
#pragma unroll
      for (int r = 0; r < 4; ++r) {
        int row = t * 16 + quad * 4 + r;
        if (row < n) {
          float v = acc[tt][r] + bv[tt];
          if constexpr (EPI == EPI_BN) v = fmaxf(v * s2[tt] + b2[tt], 0.f);
          else if constexpr (EPI == EPI_RELU) v = fmaxf(v, 0.f);
          if constexpr (OUTF32)
            ((float*)Cv)[(size_t)row * M + col] = v;
          else
            ((unsigned short*)Cv)[(size_t)row * M + col] = f2bf(v);
        }
      }
    }
  };

  auto LOADB = [&](bf16x8 (&f)[NS][KT], int t) {
    int rb = t * 16 + m16; if (rb >= n) rb = n - 1;
    const unsigned short* p0 = (const unsigned short*)A1 + (size_t)rb * K;
#pragma unroll
    for (int kt = 0; kt < KT; ++kt)
      f[0][kt] = *(const bf16x8*)(p0 + (kt * 4 + quad) * 8);
    if constexpr (NS == 2) {
      const unsigned short* p1 = (const unsigned short*)A2 + (size_t)rb * K;
#pragma unroll
      for (int kt = 0; kt < KT; ++kt)
        f[1][kt] = *(const bf16x8*)(p1 + (kt * 4 + quad) * 8);
    }
  };

  auto LOADF = [&](float4 (&f)[KT][2], int t) {   // fp32 A kept raw; pack later
    int rb = t * 16 + m16; if (rb >= n) rb = n - 1;
    const float* p = (const float*)A1 + (size_t)rb * K;
#pragma unroll
    for (int kt = 0; kt < KT; ++kt) {
      f[kt][0] = *(const float4*)(p + (kt * 4 + quad) * 8);
      f[kt][1] = *(const float4*)(p + (kt * 4 + quad) * 8 + 4);
    }
  };

  auto COMPB = [&](bf16x8 (&f)[NS][KT], int t) {
    f32x4 acc[NT];
#pragma unroll
    for (int tt = 0; tt < NT; ++tt) acc[tt] = (f32x4){0.f, 0.f, 0.f, 0.f};
#pragma unroll
    for (int kt = 0; kt < KT; ++kt) {
#pragma unroll
      for (int s = 0; s < NS; ++s) {
#pragma unroll
        for (int tt = 0; tt < NT; ++tt) {
          int brow = s * M + tt * 16 + m16;
          bf16x8 b = *(const bf16x8*)
              &Bs[brow * K + (((kt * 4 + quad) + brow) & (CH - 1)) * 8];
          acc[tt] = __builtin_amdgcn_mfma_f32_16x16x32_bf16(f[s][kt], b, acc[tt], 0, 0, 0);
        }
      }
    }
    STORE(acc, t);
  };

  auto COMPF = [&](float4 (&f)[KT][2], int t) {
    f32x4 acc[NT];
#pragma unroll
    for (int tt = 0; tt < NT; ++tt) acc[tt] = (f32x4){0.f, 0.f, 0.f, 0.f};
#pragma unroll
    for (int kt = 0; kt < KT; ++kt) {
      union { unsigned u[4]; bf16x8 v; } pk;
      pk.u[0] = pk_bf16(f[kt][0].x, f[kt][0].y);
      pk.u[1] = pk_bf16(f[kt][0].z, f[kt][0].w);
      pk.u[2] = pk_bf16(f[kt][1].x, f[kt][1].y);
      pk.u[3] = pk_bf16(f[kt][1].z, f[kt][1].w);
#pragma unroll
      for (int tt = 0; tt < NT; ++tt) {
        int brow = tt * 16 + m16;
        bf16x8 b = *(const bf16x8*)
            &Bs[brow * K + (((kt * 4 + quad) + brow) & (CH - 1)) * 8];
        acc[tt] = __builtin_amdgcn_mfma_f32_16x16x32_bf16(pk.v, b, acc[tt], 0, 0, 0);
      }
    }
    STORE(acc, t);
  };

  // ---- barrier-free grid-stride tile loop, 2-stage ping-pong pipeline ----
  int nw = gridDim.x * 4;
  int tile = blockIdx.x * 4 + wave;

  if constexpr (AFP32) {
    float4 ff0[KT][2], ff1[KT][2];
    if (tile < ntiles) LOADF(ff0, tile);
    while (tile < ntiles) {
      int t1 = tile + nw;
      if (t1 < ntiles) LOADF(ff1, t1);
      COMPF(ff0, tile);
      tile = t1;
      if (tile >= ntiles) break;
      int t2 = tile + nw;
      if (t2 < ntiles) LOADF(ff0, t2);
      COMPF(ff1, tile);
      tile = t2;
    }
  } else {
    bf16x8 fb0[NS][KT], fb1[NS][KT];
    if (tile < ntiles) LOADB(fb0, tile);
    while (tile < ntiles) {
      int t1 = tile + nw;
      if (t1 < ntiles) LOADB(fb1, t1);
      COMPB(fb0, tile);
      tile = t1;
      if (tile >= ntiles) break;
      int t2 = tile + nw;
      if (t2 < ntiles) LOADB(fb0, t2);
      COMPB(fb1, tile);
      tile = t2;
    }
  }
}

extern "C" void kernel_launch(void* const* d_in, const int* in_sizes, int n_in,
                              void* d_out, int out_size, void* d_ws, size_t ws_size,
                              hipStream_t stream) {
  const float* x     = (const float*)d_in[0];
  const int*   ei    = (const int*)d_in[1];
  const float* w_in  = (const float*)d_in[2];
  const float* b_in  = (const float*)d_in[3];
  const float* w_l1  = (const float*)d_in[4];
  const float* b_l1  = (const float*)d_in[5];
  const float* w_r1  = (const float*)d_in[6];
  const float* g1    = (const float*)d_in[7];
  const float* be1   = (const float*)d_in[8];
  const float* w_l2  = (const float*)d_in[9];
  const float* b_l2  = (const float*)d_in[10];
  const float* w_r2  = (const float*)d_in[11];
  const float* g2    = (const float*)d_in[12];
  const float* be2   = (const float*)d_in[13];
  const float* w_out = (const float*)d_in[14];
  const float* b_out = (const float*)d_in[15];
  float* out = (float*)d_out;

  int N = in_sizes[0] / DIN;
  int E = in_sizes[1] / 2;
  const int* src = ei;       // edge_index[0]
  const int* dst = ei + E;   // edge_index[1]
  int nbkt = (N + BKT_NODES - 1) / BKT_NODES;   // 782

  char* ws = (char*)d_ws;
  size_t off = 0;
  auto alloc = [&](size_t bytes) -> char* {
    char* p = ws + off;
    off += (bytes + 255) & ~(size_t)255;
    return p;
  };
  unsigned short* buf0 = (unsigned short*)alloc((size_t)N * H * 2);  // h0 -> mean2
  unsigned short* buf1 = (unsigned short*)alloc((size_t)N * H * 2);  // mean1 -> h2
  unsigned short* buf2 = (unsigned short*)alloc((size_t)N * H * 2);  // h1
  int* bcur        = (int*)alloc((size_t)nbkt * 4);
  unsigned* bedges = (unsigned*)alloc((size_t)nbkt * BKT_CAP * 4);
  int* csr         = (int*)alloc((size_t)nbkt * CSR_CAP * 4);
  int2* rowdeg     = (int2*)alloc((size_t)N * 8);
  unsigned short* t_in  = (unsigned short*)alloc(32768 * 2);
  unsigned short* t_l1  = (unsigned short*)alloc(16384 * 2);
  unsigned short* t_r1  = (unsigned short*)alloc(16384 * 2);
  unsigned short* t_l2  = (unsigned short*)alloc(16384 * 2);
  unsigned short* t_r2  = (unsigned short*)alloc(16384 * 2);
  unsigned short* t_out = (unsigned short*)alloc(8192 * 2);
  (void)ws_size;

  // ---- CSR build: bucket -> in-LDS counting sort (16B-aligned rows) ----
  hipMemsetAsync(bcur, 0, (size_t)nbkt * 4, stream);
  bucket_fill<<<(E + FILL_EPB - 1) / FILL_EPB, FILL_TPB, 0, stream>>>(
      src, dst, bcur, bedges, nbkt, E);
  bucket_sort<<<nbkt, 256, 0, stream>>>(bcur, bedges, csr, rowdeg, N);
  prep_w<<<(106496 + 255) / 256, 256, 0, stream>>>(
      w_in, w_l1, w_r1, w_l2, w_r2, w_out, t_in, t_l1, t_r1, t_l2, t_r2, t_out);

  int ntiles = (N + 15) / 16;          // 6250 16-row tiles
  int pb  = (ntiles + 11) / 12;        // 3 tiles per wave -> 521 blocks
  int pb4 = (ntiles + 7) / 8;          // 2 tiles per wave -> 782 blocks (small LDS)
  int ablocks = (N + 15) / 16;         // agg: 4 nodes/wave, 4 waves/block

  // h0 = relu(x @ w_in + b_in)            [fp32 A, native K=256]
  gemm_persist<256, 128, 1, EPI_RELU, true, false><<<pb, 256, 0, stream>>>(
      x, nullptr, t_in, nullptr, b_in, nullptr, nullptr, buf0, N, ntiles);
  // mean1
  agg_kernel<<<ablocks, 256, 0, stream>>>((const unsigned*)buf0, rowdeg,
                                          csr, (unsigned*)buf1, N);
  // h1 = relu(bn(mean1@w_l1 + h0@w_r1 + b_l1))
  gemm_persist<128, 128, 2, EPI_BN, false, false><<<pb, 256, 0, stream>>>(
      buf1, buf0, t_l1, t_r1, b_l1, g1, be1, buf2, N, ntiles);
  // mean2
  agg_kernel<<<ablocks, 256, 0, stream>>>((const unsigned*)buf2, rowdeg,
                                          csr, (unsigned*)buf0, N);
  // h2 = relu(bn(mean2@w_l2 + h1@w_r2 + b_l2))
  gemm_persist<128, 128, 2, EPI_BN, false, false><<<pb, 256, 0, stream>>>(
      buf0, buf2, t_l2, t_r2, b_l2, g2, be2, buf1, N, ntiles);
  // out = h2 @ w_out + b_out
  gemm_persist<128, 64, 1, EPI_NONE, false, true><<<pb4, 256, 0, stream>>>(
      buf1, nullptr, t_out, nullptr, b_out, nullptr, nullptr, out, N, ntiles);
}

// Round 7
// 456.445 us; speedup vs baseline: 1.0145x; 1.0145x over previous
//
#include <hip/hip_runtime.h>

#define DIN 256
#define H   128
#define DOUT 64

#define EPI_RELU 0
#define EPI_BN   1
#define EPI_NONE 2

#define BKT_SHIFT 7                 // 128 nodes per bucket
#define BKT_NODES 128
#define BKT_CAP   4096              // slots per bucket (mean 2048, sigma ~45)
#define CSR_CAP   4608              // BKT_CAP + 128*3 align slack + 16 tail pad

typedef __attribute__((ext_vector_type(8))) short bf16x8;
typedef __attribute__((ext_vector_type(4))) float f32x4;

__device__ inline unsigned short f2bf(float f) {
  union { float f; unsigned u; } v; v.f = f;
  unsigned u = v.u;
  u += 0x7FFFu + ((u >> 16) & 1u);   // round-to-nearest-even
  return (unsigned short)(u >> 16);
}
__device__ inline float bf2f(unsigned u16) {
  union { unsigned u; float f; } v; v.u = u16 << 16;
  return v.f;
}
// pack two fp32 -> one u32 of 2x bf16, RNE via verified bit-twiddle
__device__ inline unsigned pk_bf16(float lo, float hi) {
  return (unsigned)f2bf(lo) | ((unsigned)f2bf(hi) << 16);
}

// ---------------- stage 1: bucket edges by dst>>7 ----------------
#define FILL_TPB 1024
#define FILL_EPT 16
#define FILL_EPB (FILL_TPB * FILL_EPT)

__global__ __launch_bounds__(FILL_TPB) void bucket_fill(
    const int* __restrict__ src, const int* __restrict__ dst,
    int* __restrict__ bcur, unsigned* __restrict__ bedges,
    int nbkt, int e) {
  __shared__ int hist[1024];        // >= nbkt (782)
  int tid = threadIdx.x;
  int base = blockIdx.x * FILL_EPB;
  for (int i = tid; i < nbkt; i += FILL_TPB) hist[i] = 0;
  __syncthreads();

  int es[FILL_EPT], ed[FILL_EPT];
#pragma unroll
  for (int j = 0; j < FILL_EPT; ++j) {
    int i = base + j * FILL_TPB + tid;
    if (i < e) {
      es[j] = src[i];
      ed[j] = dst[i];
      atomicAdd(&hist[ed[j] >> BKT_SHIFT], 1);
    } else {
      es[j] = -1; ed[j] = 0;
    }
  }
  __syncthreads();
  for (int b = tid; b < nbkt; b += FILL_TPB) {
    int cnt = hist[b];
    hist[b] = cnt ? atomicAdd(&bcur[b], cnt) : 0;
  }
  __syncthreads();
#pragma unroll
  for (int j = 0; j < FILL_EPT; ++j) {
    if (es[j] >= 0) {
      int b = ed[j] >> BKT_SHIFT;
      int p = atomicAdd(&hist[b], 1);
      if (p < BKT_CAP)
        bedges[(size_t)b * BKT_CAP + p] =
            (unsigned)es[j] | ((unsigned)(ed[j] & (BKT_NODES - 1)) << 17);
    }
  }
}

// ---------------- stage 2: in-LDS counting sort per bucket -> aligned CSR ----
__global__ __launch_bounds__(256) void bucket_sort(
    const int* __restrict__ bcur, const unsigned* __restrict__ bedges,
    int* __restrict__ csr, int2* __restrict__ rowdeg, int n) {
  __shared__ unsigned rec[BKT_CAP];
  __shared__ int srcs[CSR_CAP];
  __shared__ int hist[BKT_NODES];
  __shared__ int cursor[BKT_NODES];
  __shared__ int s_total;
  int tid = threadIdx.x;
  int b = blockIdx.x;
  int cnt = bcur[b];
  if (cnt > BKT_CAP) cnt = BKT_CAP;
  const unsigned* eb = bedges + (size_t)b * BKT_CAP;

  if (tid < BKT_NODES) hist[tid] = 0;
  __syncthreads();
  for (int i = tid; i < cnt; i += 256) {
    unsigned r = eb[i];
    rec[i] = r;
    atomicAdd(&hist[(r >> 17) & 127], 1);
  }
  __syncthreads();
  int myc = (tid < BKT_NODES) ? hist[tid] : 0;
  int myc4 = (myc + 3) & ~3;        // 16B-aligned row length
  if (tid < BKT_NODES) hist[tid] = myc4;
  __syncthreads();
#pragma unroll
  for (int off = 1; off < BKT_NODES; off <<= 1) {
    int v = 0;
    if (tid < BKT_NODES && tid >= off) v = hist[tid - off];
    __syncthreads();
    if (tid < BKT_NODES) hist[tid] += v;
    __syncthreads();
  }
  int start = 0;
  if (tid < BKT_NODES) {
    start = hist[tid] - myc4;
    cursor[tid] = start;
    int node = b * BKT_NODES + tid;
    if (node < n) rowdeg[node] = make_int2(b * CSR_CAP + start, myc);
    if (tid == BKT_NODES - 1) s_total = hist[tid];
  }
  __syncthreads();
  for (int i = tid; i < cnt; i += 256) {
    unsigned r = rec[i];
    int p = atomicAdd(&cursor[(r >> 17) & 127], 1);
    srcs[p] = (int)(r & 0x1FFFFu);
  }
  // zero alignment gaps (disjoint from scatter targets, no sync needed)
  if (tid < BKT_NODES) {
    for (int g = start + myc; g < start + myc4; ++g) srcs[g] = 0;
  }
  __syncthreads();
  int total = s_total;
  if (tid < 16 && total + tid < CSR_CAP) srcs[total + tid] = 0;  // tail pad
  __syncthreads();
  int tot16 = total + 16;
  if (tot16 > CSR_CAP) tot16 = CSR_CAP;
  for (int i = tid; i < tot16; i += 256)
    csr[(size_t)b * CSR_CAP + i] = srcs[i];
}

// ---------------- mean aggregation: 4 nodes/wave, uint4 gather --------------
__global__ __launch_bounds__(256) void agg_kernel(
    const unsigned* __restrict__ h, const int2* __restrict__ rowdeg,
    const int* __restrict__ csr, unsigned* __restrict__ mean, int n) {
  int wid = (blockIdx.x * 256 + threadIdx.x) >> 6;
  int lane = threadIdx.x & 63;
  int grp = lane >> 4;
  int c = lane & 15;
  int node = wid * 4 + grp;
  bool valid = node < n;
  if (!valid) node = 0;
  int2 rd = rowdeg[node];
  int beg = rd.x, d = rd.y;

  const uint4* hv = (const uint4*)h;
  float a[8];
#pragma unroll
  for (int k = 0; k < 8; ++k) a[k] = 0.f;

  for (int j0 = 0; j0 < d; j0 += 16) {
    int rem = d - j0;
    const int4* sp = (const int4*)(csr + beg + j0);   // 16B aligned
    int sv[16];
    *(int4*)&sv[0]  = sp[0];
    *(int4*)&sv[4]  = sp[1];
    *(int4*)&sv[8]  = sp[2];
    *(int4*)&sv[12] = sp[3];
#pragma unroll
    for (int jj = 0; jj < 16; ++jj) {
      float w = (jj < rem) ? 1.f : 0.f;
      uint4 v = hv[(unsigned)(sv[jj] * 16 + c)];
#pragma unroll
      for (int k = 0; k < 4; ++k) {
        unsigned u = ((const unsigned*)&v)[k];
        union { unsigned u; float f; } lo, hi;
        lo.u = u << 16;
        hi.u = u & 0xffff0000u;
        a[2 * k]     = fmaf(w, lo.f, a[2 * k]);
        a[2 * k + 1] = fmaf(w, hi.f, a[2 * k + 1]);
      }
    }
  }

  if (valid) {
    float invd = 1.f / (float)(d > 0 ? d : 1);
    uint4 o;
    o.x = pk_bf16(a[0] * invd, a[1] * invd);
    o.y = pk_bf16(a[2] * invd, a[3] * invd);
    o.z = pk_bf16(a[4] * invd, a[5] * invd);
    o.w = pk_bf16(a[6] * invd, a[7] * invd);
    ((uint4*)mean)[(unsigned)(node * 16 + c)] = o;
  }
}

// ---------------- weight preconvert: Wt[m][k] = bf16(W[k][m]) ----------------
__global__ __launch_bounds__(256) void prep_w(
    const float* __restrict__ w_in, const float* __restrict__ w_l1,
    const float* __restrict__ w_r1, const float* __restrict__ w_l2,
    const float* __restrict__ w_r2, const float* __restrict__ w_out,
    unsigned short* __restrict__ t_in, unsigned short* __restrict__ t_l1,
    unsigned short* __restrict__ t_r1, unsigned short* __restrict__ t_l2,
    unsigned short* __restrict__ t_r2, unsigned short* __restrict__ t_out) {
  int i = blockIdx.x * 256 + threadIdx.x;
  const float* s; unsigned short* d; int K, M, off;
  if (i < 32768)       { s = w_in;  d = t_in;  K = 256; M = 128; off = i; }
  else if (i < 49152)  { s = w_l1;  d = t_l1;  K = 128; M = 128; off = i - 32768; }
  else if (i < 65536)  { s = w_r1;  d = t_r1;  K = 128; M = 128; off = i - 49152; }
  else if (i < 81920)  { s = w_l2;  d = t_l2;  K = 128; M = 128; off = i - 65536; }
  else if (i < 98304)  { s = w_r2;  d = t_r2;  K = 128; M = 128; off = i - 81920; }
  else if (i < 106496) { s = w_out; d = t_out; K = 128; M = 64;  off = i - 98304; }
  else return;
  int m = off / K, k = off % K;
  d[off] = f2bf(s[(size_t)k * M + m]);
}

// ------------- bf16 MFMA GEMM v6: B-in-registers, zero-sync wave GEMM -------
// One wave owns a 32-col slice (cg) of the output and keeps its B fragments
// resident in registers (16 x bf16x8 = 64 VGPR), loaded ONCE from the L2-hot
// transposed weights. It then grid-strides over independent 16-row A-tiles:
// {8-16 global A-loads -> 16 MFMA -> 8 stores}, straight-line. No LDS, no
// barriers, no DMA -> nothing ever drains the memory pipe (v4's convoy) and
// per-wave state is small (no v5 spills). 12 waves/CU x ~8KB outstanding
// covers the ~10KB/CU needed for HBM saturation via pure TLP.
// Fragment math identical to the verified v3/v4b path (minus the LDS hop):
//   A frag: A[t*16+m16][(kt*4+quad)*8 ..+8], B frag: Wt[col][(kt*4+quad)*8..+8]
//   C: row = t*16+quad*4+r, col = cg*32+tt*16+m16.
template <int K, int M, int NS, int EPI, bool AFP32, bool OUTF32, int MINW>
__global__ __launch_bounds__(256, MINW) void gemm_wave(
    const void* __restrict__ A1, const void* __restrict__ A2,
    const unsigned short* __restrict__ W1, const unsigned short* __restrict__ W2,
    const float* __restrict__ bias, const float* __restrict__ gamma,
    const float* __restrict__ beta, void* __restrict__ Cv,
    int n, int ntiles, int nwaves) {
  constexpr int CG = M / 32;        // col groups (waves sharing a row-tile)
  constexpr int NT = 2;             // 2 x 16 cols per wave
  constexpr int KT = K / 32;        // k-steps

  int tid = threadIdx.x, lane = tid & 63, wave = tid >> 6;
  int m16 = lane & 15, quad = lane >> 4;
  int wid = blockIdx.x * 4 + wave;
  int cg = wid & (CG - 1);          // constant per wave (nwaves % CG == 0)
  int t0 = wid / CG;
  int tstep = nwaves / CG;

  // ---- B fragments: resident in registers for the whole kernel ----
  bf16x8 bf[NS][KT][NT];
#pragma unroll
  for (int s = 0; s < NS; ++s) {
    const unsigned short* Ws = s ? W2 : W1;
#pragma unroll
    for (int kt = 0; kt < KT; ++kt)
#pragma unroll
      for (int tt = 0; tt < NT; ++tt) {
        int col = cg * 32 + tt * 16 + m16;
        bf[s][kt][tt] =
            *(const bf16x8*)(Ws + (size_t)col * K + (kt * 4 + quad) * 8);
      }
  }

  // ---- epilogue constants (per wave, once) ----
  const float inv_std = rsqrtf(1.f + 1e-5f);
  float bv[NT], s2[NT], b2[NT];
#pragma unroll
  for (int tt = 0; tt < NT; ++tt) {
    int col = cg * 32 + tt * 16 + m16;
    bv[tt] = bias[col];
    if constexpr (EPI == EPI_BN) {
      s2[tt] = gamma[col] * inv_std;
      b2[tt] = beta[col];
    } else {
      s2[tt] = 1.f; b2[tt] = 0.f;
    }
  }

  // ---- independent 16-row tiles; no synchronization anywhere ----
  for (int t = t0; t < ntiles; t += tstep) {
    int ra = t * 16 + m16;
    if (ra >= n) ra = n - 1;
    f32x4 acc[NT];
#pragma unroll
    for (int tt = 0; tt < NT; ++tt) acc[tt] = (f32x4){0.f, 0.f, 0.f, 0.f};

    if constexpr (!AFP32) {
      bf16x8 af[NS][KT];
#pragma unroll
      for (int s = 0; s < NS; ++s) {
        const unsigned short* Ap =
            (const unsigned short*)(s ? A2 : A1) + (size_t)ra * K;
#pragma unroll
        for (int kt = 0; kt < KT; ++kt)
          af[s][kt] = *(const bf16x8*)(Ap + (kt * 4 + quad) * 8);
      }
#pragma unroll
      for (int kt = 0; kt < KT; ++kt)
#pragma unroll
        for (int s = 0; s < NS; ++s)
#pragma unroll
          for (int tt = 0; tt < NT; ++tt)
            acc[tt] = __builtin_amdgcn_mfma_f32_16x16x32_bf16(
                af[s][kt], bf[s][kt][tt], acc[tt], 0, 0, 0);
    } else {
      float4 af[KT][2];
      const float* Ap = (const float*)A1 + (size_t)ra * K;
#pragma unroll
      for (int kt = 0; kt < KT; ++kt) {
        af[kt][0] = *(const float4*)(Ap + (kt * 4 + quad) * 8);
        af[kt][1] = *(const float4*)(Ap + (kt * 4 + quad) * 8 + 4);
      }
#pragma unroll
      for (int kt = 0; kt < KT; ++kt) {
        union { unsigned u[4]; bf16x8 v; } pk;
        pk.u[0] = pk_bf16(af[kt][0].x, af[kt][0].y);
        pk.u[1] = pk_bf16(af[kt][0].z, af[kt][0].w);
        pk.u[2] = pk_bf16(af[kt][1].x, af[kt][1].y);
        pk.u[3] = pk_bf16(af[kt][1].z, af[kt][1].w);
#pragma unroll
        for (int tt = 0; tt < NT; ++tt)
          acc[tt] = __builtin_amdgcn_mfma_f32_16x16x32_bf16(
              pk.v, bf[0][kt][tt], acc[tt], 0, 0, 0);
      }
    }

#pragma unroll
    for (int tt = 0; tt < NT; ++tt) {
      int col = cg * 32 + tt * 16 + m16;
#pragma unroll
      for (int r = 0; r < 4; ++r) {
        int row = t * 16 + quad * 4 + r;
        if (row < n) {
          float v = acc[tt][r] + bv[tt];
          if constexpr (EPI == EPI_BN) v = fmaxf(v * s2[tt] + b2[tt], 0.f);
          else if constexpr (EPI == EPI_RELU) v = fmaxf(v, 0.f);
          if constexpr (OUTF32)
            ((float*)Cv)[(size_t)row * M + col] = v;
          else
            ((unsigned short*)Cv)[(size_t)row * M + col] = f2bf(v);
        }
      }
    }
  }
}

extern "C" void kernel_launch(void* const* d_in, const int* in_sizes, int n_in,
                              void* d_out, int out_size, void* d_ws, size_t ws_size,
                              hipStream_t stream) {
  const float* x     = (const float*)d_in[0];
  const int*   ei    = (const int*)d_in[1];
  const float* w_in  = (const float*)d_in[2];
  const float* b_in  = (const float*)d_in[3];
  const float* w_l1  = (const float*)d_in[4];
  const float* b_l1  = (const float*)d_in[5];
  const float* w_r1  = (const float*)d_in[6];
  const float* g1    = (const float*)d_in[7];
  const float* be1   = (const float*)d_in[8];
  const float* w_l2  = (const float*)d_in[9];
  const float* b_l2  = (const float*)d_in[10];
  const float* w_r2  = (const float*)d_in[11];
  const float* g2    = (const float*)d_in[12];
  const float* be2   = (const float*)d_in[13];
  const float* w_out = (const float*)d_in[14];
  const float* b_out = (const float*)d_in[15];
  float* out = (float*)d_out;

  int N = in_sizes[0] / DIN;
  int E = in_sizes[1] / 2;
  const int* src = ei;       // edge_index[0]
  const int* dst = ei + E;   // edge_index[1]
  int nbkt = (N + BKT_NODES - 1) / BKT_NODES;   // 782

  char* ws = (char*)d_ws;
  size_t off = 0;
  auto alloc = [&](size_t bytes) -> char* {
    char* p = ws + off;
    off += (bytes + 255) & ~(size_t)255;
    return p;
  };
  unsigned short* buf0 = (unsigned short*)alloc((size_t)N * H * 2);  // h0 -> mean2
  unsigned short* buf1 = (unsigned short*)alloc((size_t)N * H * 2);  // mean1 -> h2
  unsigned short* buf2 = (unsigned short*)alloc((size_t)N * H * 2);  // h1
  int* bcur        = (int*)alloc((size_t)nbkt * 4);
  unsigned* bedges = (unsigned*)alloc((size_t)nbkt * BKT_CAP * 4);
  int* csr         = (int*)alloc((size_t)nbkt * CSR_CAP * 4);
  int2* rowdeg     = (int2*)alloc((size_t)N * 8);
  unsigned short* t_in  = (unsigned short*)alloc(32768 * 2);
  unsigned short* t_l1  = (unsigned short*)alloc(16384 * 2);
  unsigned short* t_r1  = (unsigned short*)alloc(16384 * 2);
  unsigned short* t_l2  = (unsigned short*)alloc(16384 * 2);
  unsigned short* t_r2  = (unsigned short*)alloc(16384 * 2);
  unsigned short* t_out = (unsigned short*)alloc(8192 * 2);
  (void)ws_size;

  // ---- CSR build: bucket -> in-LDS counting sort (16B-aligned rows) ----
  hipMemsetAsync(bcur, 0, (size_t)nbkt * 4, stream);
  bucket_fill<<<(E + FILL_EPB - 1) / FILL_EPB, FILL_TPB, 0, stream>>>(
      src, dst, bcur, bedges, nbkt, E);
  bucket_sort<<<nbkt, 256, 0, stream>>>(bcur, bedges, csr, rowdeg, N);
  prep_w<<<(106496 + 255) / 256, 256, 0, stream>>>(
      w_in, w_l1, w_r1, w_l2, w_r2, w_out, t_in, t_l1, t_r1, t_l2, t_r2, t_out);

  int ntiles = (N + 15) / 16;          // 6250 16-row tiles
  int ablocks = (N + 15) / 16;         // agg: 4 nodes/wave, 4 waves/block

  // h0 = relu(x @ w_in + b_in)      [fp32 A, K=256; CG=4; 1024 blocks]
  gemm_wave<256, 128, 1, EPI_RELU, true, false, 2><<<1024, 256, 0, stream>>>(
      x, nullptr, t_in, nullptr, b_in, nullptr, nullptr, buf0, N, ntiles, 4096);
  // mean1
  agg_kernel<<<ablocks, 256, 0, stream>>>((const unsigned*)buf0, rowdeg,
                                          csr, (unsigned*)buf1, N);
  // h1 = relu(bn(mean1@w_l1 + h0@w_r1 + b_l1))   [CG=4; 768 blocks]
  gemm_wave<128, 128, 2, EPI_BN, false, false, 3><<<768, 256, 0, stream>>>(
      buf1, buf0, t_l1, t_r1, b_l1, g1, be1, buf2, N, ntiles, 3072);
  // mean2
  agg_kernel<<<ablocks, 256, 0, stream>>>((const unsigned*)buf2, rowdeg,
                                          csr, (unsigned*)buf0, N);
  // h2 = relu(bn(mean2@w_l2 + h1@w_r2 + b_l2))
  gemm_wave<128, 128, 2, EPI_BN, false, false, 3><<<768, 256, 0, stream>>>(
      buf0, buf2, t_l2, t_r2, b_l2, g2, be2, buf1, N, ntiles, 3072);
  // out = h2 @ w_out + b_out        [CG=2; fp32 out]
  gemm_wave<128, 64, 1, EPI_NONE, false, true, 3><<<768, 256, 0, stream>>>(
      buf1, nullptr, t_out, nullptr, b_out, nullptr, nullptr, out, N, ntiles, 3072);
}